// Round 1
// baseline (1688.332 us; speedup 1.0000x reference)
//
#include <hip/hip_runtime.h>
#include <hip/hip_bf16.h>

#define N_NODES 100000
#define N_EDGES 1600000
#define DD 128
#define N_GRAPHS 512
#define BN_EPS 1e-5f

typedef unsigned int u32;
typedef __bf16 bf16_t;
typedef __bf16 bf16x2 __attribute__((ext_vector_type(2)));
typedef __bf16 bf16x4 __attribute__((ext_vector_type(4)));
typedef __bf16 bf16x8 __attribute__((ext_vector_type(8)));
typedef float f32x4 __attribute__((ext_vector_type(4)));

__device__ __forceinline__ float bfbits2f(u32 u) {
    union { u32 i; float f; } x; x.i = u << 16; return x.f;
}

// ---------------- utility kernels ----------------

__global__ void k_zero(float4* p, int n) {
    float4 z = make_float4(0.f, 0.f, 0.f, 0.f);
    for (int i = blockIdx.x * blockDim.x + threadIdx.x; i < n; i += gridDim.x * blockDim.x)
        p[i] = z;
}

__global__ void k_hist(const int* __restrict__ dst, int* __restrict__ deg) {
    for (int e = blockIdx.x * blockDim.x + threadIdx.x; e < N_EDGES; e += gridDim.x * blockDim.x)
        atomicAdd(&deg[dst[e]], 1);
}

// single block, 1024 threads: exclusive scan of deg -> offs, copy to cursor
__global__ void k_scan(const int* __restrict__ deg, int* __restrict__ offs, int* __restrict__ cursor) {
    __shared__ int ps[1024];
    const int CH = 98; // ceil(100000/1024)
    int t = threadIdx.x;
    int begI = t * CH;
    int endI = begI + CH; if (endI > N_NODES) endI = N_NODES;
    int s = 0;
    for (int i = begI; i < endI; ++i) s += deg[i];
    ps[t] = s;
    __syncthreads();
    for (int d2 = 1; d2 < 1024; d2 <<= 1) {
        int v = (t >= d2) ? ps[t - d2] : 0;
        __syncthreads();
        ps[t] += v;
        __syncthreads();
    }
    int run = ps[t] - s; // exclusive prefix of this chunk
    for (int i = begI; i < endI; ++i) {
        offs[i] = run; cursor[i] = run;
        run += deg[i];
    }
    if (t == 1023) offs[N_NODES] = ps[1023];
}

__global__ void k_fill(const int* __restrict__ src, const int* __restrict__ dst,
                       int* __restrict__ cursor, int* __restrict__ csr) {
    for (int e = blockIdx.x * blockDim.x + threadIdx.x; e < N_EDGES; e += gridDim.x * blockDim.x) {
        int pos = atomicAdd(&cursor[dst[e]], 1);
        csr[pos] = src[e];
    }
}

__global__ void k_cvt(const float* __restrict__ x, bf16_t* __restrict__ xb) {
    const int n4 = N_NODES * DD / 4;
    const float4* x4 = (const float4*)x;
    bf16x4* o4 = (bf16x4*)xb;
    for (int i = blockIdx.x * blockDim.x + threadIdx.x; i < n4; i += gridDim.x * blockDim.x) {
        float4 v = x4[i];
        bf16x4 o;
        o.x = (bf16_t)v.x; o.y = (bf16_t)v.y; o.z = (bf16_t)v.z; o.w = (bf16_t)v.w;
        o4[i] = o;
    }
}

// Pre-shuffle the 6 weight matrices into exact MFMA B-fragment order (bf16).
// wshuf[g][((ks*8+nt)*64 + lane)*8 + j] = W_g[ks*32 + (lane>>4)*8 + j][nt*16 + (lane&15)]
__global__ void k_shufw(const float* __restrict__ W1s, const float* __restrict__ W2s,
                        bf16_t* __restrict__ wshuf) {
    int t = blockIdx.x * blockDim.x + threadIdx.x;
    if (t >= 6 * 16384) return;
    int g  = t >> 14;
    int r  = t & 16383;
    int j  = r & 7;
    int L  = (r >> 3) & 63;
    int nt = (r >> 9) & 7;
    int ks = r >> 12;
    int l  = g >> 1;
    const float* src = (g & 1) ? (W2s + l * 16384) : (W1s + l * 16384);
    int k = ks * 32 + (L >> 4) * 8 + j;
    int n = nt * 16 + (L & 15);
    wshuf[t] = (bf16_t)src[k * DD + n];
}

__global__ void k_aff_init(float* __restrict__ ss) {
    int f = threadIdx.x;
    if (f < DD) { ss[f] = 1.0f; ss[DD + f] = 0.0f; }
}

__global__ void k_aff_update(const float* __restrict__ stats, const float* __restrict__ gamma,
                             const float* __restrict__ beta, float* __restrict__ scale,
                             float* __restrict__ shift) {
    int f = threadIdx.x;
    if (f < DD) {
        float mu  = stats[f] * (1.0f / N_NODES);
        float var = stats[DD + f] * (1.0f / N_NODES) - mu * mu;
        float inv = rsqrtf(var + BN_EPS);
        float sc  = gamma[f] * inv;
        scale[f] = sc;
        shift[f] = beta[f] - mu * sc;
    }
}

// ---------------- fused GIN layer ----------------
// block = 256 threads (4 waves), 64 nodes. Phase1 gather -> LDS; Phase2 GEMM1; Phase3 GEMM2+BN stats.
__global__ __launch_bounds__(256) void k_layer(
    const bf16_t* __restrict__ xb, bf16_t* __restrict__ yb,
    const int* __restrict__ offs, const int* __restrict__ csr,
    const float* __restrict__ scale, const float* __restrict__ shift,
    const bf16_t* __restrict__ w1s, const bf16_t* __restrict__ w2s,
    const float* __restrict__ b1, const float* __restrict__ b2,
    float* __restrict__ stats)
{
    __shared__ __align__(16) bf16_t aggT[64 * 136];
    __shared__ __align__(16) bf16_t h1T[64 * 136];

    const int tid  = threadIdx.x;
    const int w    = tid >> 6;
    const int lane = tid & 63;
    const int base = blockIdx.x * 64;

    // ---- Phase 1: each wave aggregates 16 rows; lane covers 2 features ----
    const u32* xbu = (const u32*)xb; // 64 uints per row
    const int f2 = lane * 2;
    const float sc0 = scale[f2], sc1 = scale[f2 + 1];
    const float sh0 = shift[f2], sh1 = shift[f2 + 1];

    for (int r = 0; r < 16; ++r) {
        int row = (w << 4) + r;
        int node = base + row;
        float a0 = 0.f, a1 = 0.f;
        if (node < N_NODES) {
            u32 self = xbu[node * 64 + lane];
            a0 = bfbits2f(self & 0xffffu);
            a1 = bfbits2f(self >> 16);
            int e0 = offs[node], e1 = offs[node + 1];
            float cntf = (float)(e1 - e0 + 1);
            int e = e0;
            for (; e + 4 <= e1; e += 4) {
                int s0 = csr[e + 0], s1i = csr[e + 1], s2i = csr[e + 2], s3i = csr[e + 3];
                u32 u0 = xbu[s0 * 64 + lane];
                u32 u1 = xbu[s1i * 64 + lane];
                u32 u2 = xbu[s2i * 64 + lane];
                u32 u3 = xbu[s3i * 64 + lane];
                a0 += bfbits2f(u0 & 0xffffu) + bfbits2f(u1 & 0xffffu) +
                      bfbits2f(u2 & 0xffffu) + bfbits2f(u3 & 0xffffu);
                a1 += bfbits2f(u0 >> 16) + bfbits2f(u1 >> 16) +
                      bfbits2f(u2 >> 16) + bfbits2f(u3 >> 16);
            }
            for (; e < e1; ++e) {
                u32 u = xbu[csr[e] * 64 + lane];
                a0 += bfbits2f(u & 0xffffu);
                a1 += bfbits2f(u >> 16);
            }
            a0 = a0 * sc0 + cntf * sh0;
            a1 = a1 * sc1 + cntf * sh1;
        }
        bf16x2 pk; pk.x = (bf16_t)a0; pk.y = (bf16_t)a1;
        *(bf16x2*)(&aggT[row * 136 + f2]) = pk;
    }
    __syncthreads();

    // ---- Phase 2: GEMM1 (64x128 @ 128x128) + bias + relu -> h1T ----
    const int q = lane >> 4;
    const int c = lane & 15;
    const int arow = (w << 4) + c;

    bf16x8 afr[4];
#pragma unroll
    for (int ks = 0; ks < 4; ++ks)
        afr[ks] = *(const bf16x8*)(&aggT[arow * 136 + ks * 32 + q * 8]);

    f32x4 acc[8];
#pragma unroll
    for (int nt = 0; nt < 8; ++nt) acc[nt] = (f32x4){0.f, 0.f, 0.f, 0.f};
#pragma unroll
    for (int ks = 0; ks < 4; ++ks) {
#pragma unroll
        for (int nt = 0; nt < 8; ++nt) {
            bf16x8 bfr = *(const bf16x8*)(w1s + (((ks << 3) + nt) * 64 + lane) * 8);
            acc[nt] = __builtin_amdgcn_mfma_f32_16x16x32_bf16(afr[ks], bfr, acc[nt], 0, 0, 0);
        }
    }
#pragma unroll
    for (int nt = 0; nt < 8; ++nt) {
        float bias = b1[(nt << 4) + c];
#pragma unroll
        for (int i = 0; i < 4; ++i) {
            float v = fmaxf(acc[nt][i] + bias, 0.f);
            int row = (w << 4) + (q << 2) + i;
            h1T[row * 136 + (nt << 4) + c] = (bf16_t)v;
        }
    }
    __syncthreads();

    // ---- Phase 3: GEMM2 + bias + relu + BN stats + store ----
    bf16x8 afr2[4];
#pragma unroll
    for (int ks = 0; ks < 4; ++ks)
        afr2[ks] = *(const bf16x8*)(&h1T[arow * 136 + ks * 32 + q * 8]);

#pragma unroll
    for (int nt = 0; nt < 8; ++nt) acc[nt] = (f32x4){0.f, 0.f, 0.f, 0.f};
#pragma unroll
    for (int ks = 0; ks < 4; ++ks) {
#pragma unroll
        for (int nt = 0; nt < 8; ++nt) {
            bf16x8 bfr = *(const bf16x8*)(w2s + (((ks << 3) + nt) * 64 + lane) * 8);
            acc[nt] = __builtin_amdgcn_mfma_f32_16x16x32_bf16(afr2[ks], bfr, acc[nt], 0, 0, 0);
        }
    }
#pragma unroll
    for (int nt = 0; nt < 8; ++nt) {
        float bias = b2[(nt << 4) + c];
        float s1 = 0.f, s2 = 0.f;
#pragma unroll
        for (int i = 0; i < 4; ++i) {
            float v = fmaxf(acc[nt][i] + bias, 0.f);
            int row = (w << 4) + (q << 2) + i;
            int node = base + row;
            if (node < N_NODES) {
                s1 += v;
                s2 += v * v;
                yb[node * DD + (nt << 4) + c] = (bf16_t)v;
            }
        }
        s1 += __shfl_down(s1, 32); s2 += __shfl_down(s2, 32);
        s1 += __shfl_down(s1, 16); s2 += __shfl_down(s2, 16);
        if (lane < 16) {
            atomicAdd(&stats[(nt << 4) + lane], s1);
            atomicAdd(&stats[DD + (nt << 4) + lane], s2);
        }
    }
}

// ---------------- pooling + head ----------------

__global__ void k_pool(const bf16_t* __restrict__ yb, const int* __restrict__ batch,
                       const float* __restrict__ scale, const float* __restrict__ shift,
                       float* __restrict__ sums, float* __restrict__ cnt) {
    const int total = N_NODES * 32;
    for (int t = blockIdx.x * blockDim.x + threadIdx.x; t < total; t += gridDim.x * blockDim.x) {
        int node = t >> 5;
        int f4 = (t & 31) << 2;
        int g = batch[node];
        uint2 u = *(const uint2*)(yb + node * DD + f4);
        float v0 = bfbits2f(u.x & 0xffffu) * scale[f4 + 0] + shift[f4 + 0];
        float v1 = bfbits2f(u.x >> 16)     * scale[f4 + 1] + shift[f4 + 1];
        float v2 = bfbits2f(u.y & 0xffffu) * scale[f4 + 2] + shift[f4 + 2];
        float v3 = bfbits2f(u.y >> 16)     * scale[f4 + 3] + shift[f4 + 3];
        atomicAdd(&sums[g * DD + f4 + 0], v0);
        atomicAdd(&sums[g * DD + f4 + 1], v1);
        atomicAdd(&sums[g * DD + f4 + 2], v2);
        atomicAdd(&sums[g * DD + f4 + 3], v3);
        if ((t & 31) == 0) atomicAdd(&cnt[g], 1.0f);
    }
}

__global__ void k_head(const float* __restrict__ sums, const float* __restrict__ cnt,
                       const float* __restrict__ lin1w, const float* __restrict__ lin1b,
                       const float* __restrict__ lin2w, const float* __restrict__ lin2b,
                       float* __restrict__ out) {
    __shared__ float p[DD];
    __shared__ float h[DD];
    int g = blockIdx.x;
    int t = threadIdx.x;
    float cc = fmaxf(cnt[g], 1.0f);
    p[t] = sums[g * DD + t] / cc;
    __syncthreads();
    float a = lin1b[t];
    for (int k = 0; k < DD; ++k) a += p[k] * lin1w[k * DD + t];
    h[t] = fmaxf(a, 0.f);
    __syncthreads();
    if (t < 10) {
        float o = lin2b[t];
        for (int k = 0; k < DD; ++k) o += h[k] * lin2w[k * 10 + t];
        out[g * 10 + t] = o;
    }
}

// ---------------- launch ----------------

extern "C" void kernel_launch(void* const* d_in, const int* in_sizes, int n_in,
                              void* d_out, int out_size, void* d_ws, size_t ws_size,
                              hipStream_t stream) {
    const float* x      = (const float*)d_in[0];
    const int*   ei     = (const int*)d_in[1];
    const int*   batch  = (const int*)d_in[2];
    const float* W1s    = (const float*)d_in[3];
    const float* b1s    = (const float*)d_in[4];
    const float* W2s    = (const float*)d_in[5];
    const float* b2s    = (const float*)d_in[6];
    const float* gammas = (const float*)d_in[7];
    const float* betas  = (const float*)d_in[8];
    const float* lin1w  = (const float*)d_in[9];
    const float* lin1b  = (const float*)d_in[10];
    const float* lin2w  = (const float*)d_in[11];
    const float* lin2b  = (const float*)d_in[12];
    float* out = (float*)d_out;

    char* p = (char*)d_ws;
    size_t off = 0;
    auto alloc = [&](size_t bytes) -> char* {
        char* r = p + off;
        off += (bytes + 255) & ~(size_t)255;
        return r;
    };
    int*    deg    = (int*)alloc(N_NODES * 4);
    float*  stats  = (float*)alloc(3 * 256 * 4);
    float*  sums   = (float*)alloc(N_GRAPHS * DD * 4);
    float*  cnt    = (float*)alloc(N_GRAPHS * 4);
    size_t zero_bytes = off;
    int*    offs   = (int*)alloc((N_NODES + 1) * 4);
    int*    cursor = (int*)alloc(N_NODES * 4);
    int*    csr    = (int*)alloc(N_EDGES * 4);
    bf16_t* xb     = (bf16_t*)alloc((size_t)N_NODES * DD * 2);
    bf16_t* yb     = (bf16_t*)alloc((size_t)N_NODES * DD * 2);
    bf16_t* wshuf  = (bf16_t*)alloc(6 * 16384 * 2);
    float*  ss     = (float*)alloc(4 * 256 * 4); // scale_l at ss+l*256, shift at +128
    if (off > ws_size) return;

    const int* srcA = ei;
    const int* dstA = ei + N_EDGES;

    k_zero<<<256, 256, 0, stream>>>((float4*)d_ws, (int)(zero_bytes / 16));
    k_hist<<<1024, 256, 0, stream>>>(dstA, deg);
    k_scan<<<1, 1024, 0, stream>>>(deg, offs, cursor);
    k_fill<<<1024, 256, 0, stream>>>(srcA, dstA, cursor, csr);
    k_cvt<<<1024, 256, 0, stream>>>(x, xb);
    k_shufw<<<(6 * 16384 + 255) / 256, 256, 0, stream>>>(W1s, W2s, wshuf);
    k_aff_init<<<1, 128, 0, stream>>>(ss);

    bf16_t* bufs[2] = { xb, yb };
    for (int l = 0; l < 3; ++l) {
        k_layer<<<(N_NODES + 63) / 64, 256, 0, stream>>>(
            bufs[l & 1], bufs[(l + 1) & 1], offs, csr,
            ss + l * 256, ss + l * 256 + 128,
            wshuf + (2 * l) * 16384, wshuf + (2 * l + 1) * 16384,
            b1s + l * DD, b2s + l * DD, stats + l * 256);
        k_aff_update<<<1, 128, 0, stream>>>(stats + l * 256, gammas + l * DD, betas + l * DD,
                                            ss + (l + 1) * 256, ss + (l + 1) * 256 + 128);
    }
    k_pool<<<2048, 256, 0, stream>>>(bufs[1], batch, ss + 3 * 256, ss + 3 * 256 + 128, sums, cnt);
    k_head<<<N_GRAPHS, 128, 0, stream>>>(sums, cnt, lin1w, lin1b, lin2w, lin2b, out);
}

// Round 2
// 1450.422 us; speedup vs baseline: 1.1640x; 1.1640x over previous
//
#include <hip/hip_runtime.h>
#include <hip/hip_bf16.h>

#define N_NODES 100000
#define N_EDGES 1600000
#define DD 128
#define N_GRAPHS 512
#define BN_EPS 1e-5f

typedef unsigned int u32;
typedef __bf16 bf16_t;
typedef __bf16 bf16x2 __attribute__((ext_vector_type(2)));
typedef __bf16 bf16x4 __attribute__((ext_vector_type(4)));
typedef __bf16 bf16x8 __attribute__((ext_vector_type(8)));
typedef float f32x4 __attribute__((ext_vector_type(4)));

__device__ __forceinline__ float bfbits2f(u32 u) {
    union { u32 i; float f; } x; x.i = u << 16; return x.f;
}

// ---------------- utility kernels ----------------

__global__ void k_zero(float4* p, int n) {
    float4 z = make_float4(0.f, 0.f, 0.f, 0.f);
    for (int i = blockIdx.x * blockDim.x + threadIdx.x; i < n; i += gridDim.x * blockDim.x)
        p[i] = z;
}

__global__ void k_hist(const int* __restrict__ dst, int* __restrict__ deg) {
    for (int e = blockIdx.x * blockDim.x + threadIdx.x; e < N_EDGES; e += gridDim.x * blockDim.x)
        atomicAdd(&deg[dst[e]], 1);
}

// single block, 1024 threads: exclusive scan of deg -> offs, copy to cursor
__global__ void k_scan(const int* __restrict__ deg, int* __restrict__ offs, int* __restrict__ cursor) {
    __shared__ int ps[1024];
    const int CH = 98; // ceil(100000/1024)
    int t = threadIdx.x;
    int begI = t * CH;
    int endI = begI + CH; if (endI > N_NODES) endI = N_NODES;
    int s = 0;
    for (int i = begI; i < endI; ++i) s += deg[i];
    ps[t] = s;
    __syncthreads();
    for (int d2 = 1; d2 < 1024; d2 <<= 1) {
        int v = (t >= d2) ? ps[t - d2] : 0;
        __syncthreads();
        ps[t] += v;
        __syncthreads();
    }
    int run = ps[t] - s; // exclusive prefix of this chunk
    for (int i = begI; i < endI; ++i) {
        offs[i] = run; cursor[i] = run;
        run += deg[i];
    }
    if (t == 1023) offs[N_NODES] = ps[1023];
}

__global__ void k_fill(const int* __restrict__ src, const int* __restrict__ dst,
                       int* __restrict__ cursor, int* __restrict__ csr) {
    for (int e = blockIdx.x * blockDim.x + threadIdx.x; e < N_EDGES; e += gridDim.x * blockDim.x) {
        int pos = atomicAdd(&cursor[dst[e]], 1);
        csr[pos] = src[e];
    }
}

__global__ void k_cvt(const float* __restrict__ x, bf16_t* __restrict__ xb) {
    const int n4 = N_NODES * DD / 4;
    const float4* x4 = (const float4*)x;
    bf16x4* o4 = (bf16x4*)xb;
    for (int i = blockIdx.x * blockDim.x + threadIdx.x; i < n4; i += gridDim.x * blockDim.x) {
        float4 v = x4[i];
        bf16x4 o;
        o.x = (bf16_t)v.x; o.y = (bf16_t)v.y; o.z = (bf16_t)v.z; o.w = (bf16_t)v.w;
        o4[i] = o;
    }
}

// Pre-shuffle the 6 weight matrices into exact MFMA B-fragment order (bf16).
// wshuf[g][((ks*8+nt)*64 + lane)*8 + j] = W_g[ks*32 + (lane>>4)*8 + j][nt*16 + (lane&15)]
__global__ void k_shufw(const float* __restrict__ W1s, const float* __restrict__ W2s,
                        bf16_t* __restrict__ wshuf) {
    int t = blockIdx.x * blockDim.x + threadIdx.x;
    if (t >= 6 * 16384) return;
    int g  = t >> 14;
    int r  = t & 16383;
    int j  = r & 7;
    int L  = (r >> 3) & 63;
    int nt = (r >> 9) & 7;
    int ks = r >> 12;
    int l  = g >> 1;
    const float* src = (g & 1) ? (W2s + l * 16384) : (W1s + l * 16384);
    int k = ks * 32 + (L >> 4) * 8 + j;
    int n = nt * 16 + (L & 15);
    wshuf[t] = (bf16_t)src[k * DD + n];
}

__global__ void k_aff_init(float* __restrict__ ss) {
    int f = threadIdx.x;
    if (f < DD) { ss[f] = 1.0f; ss[DD + f] = 0.0f; }
}

__global__ void k_aff_update(const float* __restrict__ stats, const float* __restrict__ gamma,
                             const float* __restrict__ beta, float* __restrict__ scale,
                             float* __restrict__ shift) {
    int f = threadIdx.x;
    if (f < DD) {
        float mu  = stats[f] * (1.0f / N_NODES);
        float var = stats[DD + f] * (1.0f / N_NODES) - mu * mu;
        float inv = rsqrtf(var + BN_EPS);
        float sc  = gamma[f] * inv;
        scale[f] = sc;
        shift[f] = beta[f] - mu * sc;
    }
}

// graph boundary finder: gstart[g] = first node index with batch[node] >= g
__global__ void k_gbounds(const int* __restrict__ batch, int* __restrict__ gstart) {
    int i = blockIdx.x * blockDim.x + threadIdx.x;
    if (i >= N_NODES) return;
    int b = batch[i];
    int bp = (i == 0) ? -1 : batch[i - 1];
    for (int g = bp + 1; g <= b; ++g) gstart[g] = i;
    if (i == N_NODES - 1)
        for (int g = b + 1; g <= N_GRAPHS; ++g) gstart[g] = N_NODES;
}

// ---------------- fused GIN layer ----------------
// block = 256 threads (4 waves), 64 nodes. Phase1 gather -> LDS; Phase2 GEMM1; Phase3 GEMM2+BN stats.
__global__ __launch_bounds__(256) void k_layer(
    const bf16_t* __restrict__ xb, bf16_t* __restrict__ yb,
    const int* __restrict__ offs, const int* __restrict__ csr,
    const float* __restrict__ scale, const float* __restrict__ shift,
    const bf16_t* __restrict__ w1s, const bf16_t* __restrict__ w2s,
    const float* __restrict__ b1, const float* __restrict__ b2,
    float* __restrict__ stats)
{
    __shared__ __align__(16) bf16_t aggT[64 * 136];
    __shared__ __align__(16) bf16_t h1T[64 * 136];

    const int tid  = threadIdx.x;
    const int w    = tid >> 6;
    const int lane = tid & 63;
    const int base = blockIdx.x * 64;

    // ---- Phase 1: each wave aggregates 16 rows; lane covers 2 features ----
    const u32* xbu = (const u32*)xb; // 64 uints per row
    const int f2 = lane * 2;
    const float sc0 = scale[f2], sc1 = scale[f2 + 1];
    const float sh0 = shift[f2], sh1 = shift[f2 + 1];

    for (int r = 0; r < 16; ++r) {
        int row = (w << 4) + r;
        int node = base + row;
        float a0 = 0.f, a1 = 0.f;
        if (node < N_NODES) {
            u32 self = xbu[node * 64 + lane];
            a0 = bfbits2f(self & 0xffffu);
            a1 = bfbits2f(self >> 16);
            int e0 = offs[node], e1 = offs[node + 1];
            float cntf = (float)(e1 - e0 + 1);
            int e = e0;
            for (; e + 4 <= e1; e += 4) {
                int s0 = csr[e + 0], s1i = csr[e + 1], s2i = csr[e + 2], s3i = csr[e + 3];
                u32 u0 = xbu[s0 * 64 + lane];
                u32 u1 = xbu[s1i * 64 + lane];
                u32 u2 = xbu[s2i * 64 + lane];
                u32 u3 = xbu[s3i * 64 + lane];
                a0 += bfbits2f(u0 & 0xffffu) + bfbits2f(u1 & 0xffffu) +
                      bfbits2f(u2 & 0xffffu) + bfbits2f(u3 & 0xffffu);
                a1 += bfbits2f(u0 >> 16) + bfbits2f(u1 >> 16) +
                      bfbits2f(u2 >> 16) + bfbits2f(u3 >> 16);
            }
            for (; e < e1; ++e) {
                u32 u = xbu[csr[e] * 64 + lane];
                a0 += bfbits2f(u & 0xffffu);
                a1 += bfbits2f(u >> 16);
            }
            a0 = a0 * sc0 + cntf * sh0;
            a1 = a1 * sc1 + cntf * sh1;
        }
        bf16x2 pk; pk.x = (bf16_t)a0; pk.y = (bf16_t)a1;
        *(bf16x2*)(&aggT[row * 136 + f2]) = pk;
    }
    __syncthreads();

    // ---- Phase 2: GEMM1 (64x128 @ 128x128) + bias + relu -> h1T ----
    const int q = lane >> 4;
    const int c = lane & 15;
    const int arow = (w << 4) + c;

    bf16x8 afr[4];
#pragma unroll
    for (int ks = 0; ks < 4; ++ks)
        afr[ks] = *(const bf16x8*)(&aggT[arow * 136 + ks * 32 + q * 8]);

    f32x4 acc[8];
#pragma unroll
    for (int nt = 0; nt < 8; ++nt) acc[nt] = (f32x4){0.f, 0.f, 0.f, 0.f};
#pragma unroll
    for (int ks = 0; ks < 4; ++ks) {
#pragma unroll
        for (int nt = 0; nt < 8; ++nt) {
            bf16x8 bfr = *(const bf16x8*)(w1s + (((ks << 3) + nt) * 64 + lane) * 8);
            acc[nt] = __builtin_amdgcn_mfma_f32_16x16x32_bf16(afr[ks], bfr, acc[nt], 0, 0, 0);
        }
    }
#pragma unroll
    for (int nt = 0; nt < 8; ++nt) {
        float bias = b1[(nt << 4) + c];
#pragma unroll
        for (int i = 0; i < 4; ++i) {
            float v = fmaxf(acc[nt][i] + bias, 0.f);
            int row = (w << 4) + (q << 2) + i;
            h1T[row * 136 + (nt << 4) + c] = (bf16_t)v;
        }
    }
    __syncthreads();

    // ---- Phase 3: GEMM2 + bias + relu + BN stats + store ----
    bf16x8 afr2[4];
#pragma unroll
    for (int ks = 0; ks < 4; ++ks)
        afr2[ks] = *(const bf16x8*)(&h1T[arow * 136 + ks * 32 + q * 8]);

#pragma unroll
    for (int nt = 0; nt < 8; ++nt) acc[nt] = (f32x4){0.f, 0.f, 0.f, 0.f};
#pragma unroll
    for (int ks = 0; ks < 4; ++ks) {
#pragma unroll
        for (int nt = 0; nt < 8; ++nt) {
            bf16x8 bfr = *(const bf16x8*)(w2s + (((ks << 3) + nt) * 64 + lane) * 8);
            acc[nt] = __builtin_amdgcn_mfma_f32_16x16x32_bf16(afr2[ks], bfr, acc[nt], 0, 0, 0);
        }
    }
#pragma unroll
    for (int nt = 0; nt < 8; ++nt) {
        float bias = b2[(nt << 4) + c];
        float s1 = 0.f, s2 = 0.f;
#pragma unroll
        for (int i = 0; i < 4; ++i) {
            float v = fmaxf(acc[nt][i] + bias, 0.f);
            int row = (w << 4) + (q << 2) + i;
            int node = base + row;
            if (node < N_NODES) {
                s1 += v;
                s2 += v * v;
                yb[node * DD + (nt << 4) + c] = (bf16_t)v;
            }
        }
        s1 += __shfl_down(s1, 32); s2 += __shfl_down(s2, 32);
        s1 += __shfl_down(s1, 16); s2 += __shfl_down(s2, 16);
        if (lane < 16) {
            atomicAdd(&stats[(nt << 4) + lane], s1);
            atomicAdd(&stats[DD + (nt << 4) + lane], s2);
        }
    }
}

// ---------------- pooling + head ----------------

// one block per graph; batch is sorted so each graph is a contiguous node range.
// Zero atomics: segmented reduction with BN affine + mean folded in.
__global__ __launch_bounds__(128) void k_pool2(
    const bf16_t* __restrict__ yb, const int* __restrict__ gstart,
    const float* __restrict__ scale, const float* __restrict__ shift,
    float* __restrict__ pooled)
{
    int g = blockIdx.x;
    int t = threadIdx.x;
    int s = gstart[g], e = gstart[g + 1];
    float acc = 0.f;
    for (int n = s; n < e; ++n)
        acc += (float)yb[n * DD + t];
    float cnt = (float)(e - s);
    float v = acc * scale[t] + cnt * shift[t];
    pooled[g * DD + t] = v / fmaxf(cnt, 1.0f);
}

__global__ void k_head(const float* __restrict__ pooled,
                       const float* __restrict__ lin1w, const float* __restrict__ lin1b,
                       const float* __restrict__ lin2w, const float* __restrict__ lin2b,
                       float* __restrict__ out) {
    __shared__ float p[DD];
    __shared__ float h[DD];
    int g = blockIdx.x;
    int t = threadIdx.x;
    p[t] = pooled[g * DD + t];
    __syncthreads();
    float a = lin1b[t];
    for (int k = 0; k < DD; ++k) a += p[k] * lin1w[k * DD + t];
    h[t] = fmaxf(a, 0.f);
    __syncthreads();
    if (t < 10) {
        float o = lin2b[t];
        for (int k = 0; k < DD; ++k) o += h[k] * lin2w[k * 10 + t];
        out[g * 10 + t] = o;
    }
}

// ---------------- launch ----------------

extern "C" void kernel_launch(void* const* d_in, const int* in_sizes, int n_in,
                              void* d_out, int out_size, void* d_ws, size_t ws_size,
                              hipStream_t stream) {
    const float* x      = (const float*)d_in[0];
    const int*   ei     = (const int*)d_in[1];
    const int*   batch  = (const int*)d_in[2];
    const float* W1s    = (const float*)d_in[3];
    const float* b1s    = (const float*)d_in[4];
    const float* W2s    = (const float*)d_in[5];
    const float* b2s    = (const float*)d_in[6];
    const float* gammas = (const float*)d_in[7];
    const float* betas  = (const float*)d_in[8];
    const float* lin1w  = (const float*)d_in[9];
    const float* lin1b  = (const float*)d_in[10];
    const float* lin2w  = (const float*)d_in[11];
    const float* lin2b  = (const float*)d_in[12];
    float* out = (float*)d_out;

    char* p = (char*)d_ws;
    size_t off = 0;
    auto alloc = [&](size_t bytes) -> char* {
        char* r = p + off;
        off += (bytes + 255) & ~(size_t)255;
        return r;
    };
    int*    deg    = (int*)alloc(N_NODES * 4);
    float*  stats  = (float*)alloc(3 * 256 * 4);
    size_t zero_bytes = off;
    int*    offs   = (int*)alloc((N_NODES + 1) * 4);
    int*    cursor = (int*)alloc(N_NODES * 4);
    int*    csr    = (int*)alloc(N_EDGES * 4);
    bf16_t* xb     = (bf16_t*)alloc((size_t)N_NODES * DD * 2);
    bf16_t* yb     = (bf16_t*)alloc((size_t)N_NODES * DD * 2);
    bf16_t* wshuf  = (bf16_t*)alloc(6 * 16384 * 2);
    float*  ss     = (float*)alloc(4 * 256 * 4); // scale_l at ss+l*256, shift at +128
    int*    gstart = (int*)alloc((N_GRAPHS + 1) * 4);
    float*  pooled = (float*)alloc(N_GRAPHS * DD * 4);
    if (off > ws_size) return;

    const int* srcA = ei;
    const int* dstA = ei + N_EDGES;

    k_zero<<<256, 256, 0, stream>>>((float4*)d_ws, (int)(zero_bytes / 16));
    k_hist<<<1024, 256, 0, stream>>>(dstA, deg);
    k_scan<<<1, 1024, 0, stream>>>(deg, offs, cursor);
    k_fill<<<1024, 256, 0, stream>>>(srcA, dstA, cursor, csr);
    k_cvt<<<1024, 256, 0, stream>>>(x, xb);
    k_shufw<<<(6 * 16384 + 255) / 256, 256, 0, stream>>>(W1s, W2s, wshuf);
    k_aff_init<<<1, 128, 0, stream>>>(ss);
    k_gbounds<<<(N_NODES + 255) / 256, 256, 0, stream>>>(batch, gstart);

    bf16_t* bufs[2] = { xb, yb };
    for (int l = 0; l < 3; ++l) {
        k_layer<<<(N_NODES + 63) / 64, 256, 0, stream>>>(
            bufs[l & 1], bufs[(l + 1) & 1], offs, csr,
            ss + l * 256, ss + l * 256 + 128,
            wshuf + (2 * l) * 16384, wshuf + (2 * l + 1) * 16384,
            b1s + l * DD, b2s + l * DD, stats + l * 256);
        k_aff_update<<<1, 128, 0, stream>>>(stats + l * 256, gammas + l * DD, betas + l * DD,
                                            ss + (l + 1) * 256, ss + (l + 1) * 256 + 128);
    }
    k_pool2<<<N_GRAPHS, 128, 0, stream>>>(bufs[1], gstart, ss + 3 * 256, ss + 3 * 256 + 128, pooled);
    k_head<<<N_GRAPHS, 128, 0, stream>>>(pooled, lin1w, lin1b, lin2w, lin2b, out);
}